// Round 2
// baseline (88.094 us; speedup 1.0000x reference)
//
#include <hip/hip_runtime.h>
#include <math.h>

#define NSESS 2048
#define L 128
#define IDCG_FLOOR 1e-5f

__global__ __launch_bounds__(L) void lambdarank_ndcg_kernel(
    const float* __restrict__ logit,
    const float* __restrict__ label,
    float* __restrict__ out_loss,   // [NSESS]
    float* __restrict__ out_grad)   // [NSESS * L]
{
    __shared__ float s_pred[L];
    __shared__ float s_label[L];
    __shared__ float s_gain[L];
    __shared__ float s_disc[L];
    __shared__ float s_dcg[2];
    __shared__ float s_idcg[2];

    const int b = blockIdx.x;
    const int i = threadIdx.x;
    const int base = b * L;

    const float p  = logit[base + i];
    const float lb = label[base + i];
    s_pred[i]  = p;
    s_label[i] = lb;
    __syncthreads();

    // Rank under descending stable sort: rank(i) = #{j: v[j]>v[i]} + #{j<i: v[j]==v[i]}
    int rank_p = 0, rank_l = 0;
    #pragma unroll 8
    for (int j = 0; j < L; ++j) {
        const float pj = s_pred[j];
        const float lj = s_label[j];
        rank_p += (pj > p)  || (pj == p  && j < i);
        rank_l += (lj > lb) || (lj == lb && j < i);
    }

    const float gain  = exp2f(lb);
    const float pdisc = 1.0f / log2f((float)(rank_p + 2));
    const float ldisc = 1.0f / log2f((float)(rank_l + 2));

    s_gain[i] = gain;
    s_disc[i] = pdisc;

    // Block reduction of dcg = gain@pred_disc, idcg = gain@label_disc
    float dcg  = gain * pdisc;
    float idcg = gain * ldisc;
    #pragma unroll
    for (int off = 32; off > 0; off >>= 1) {
        dcg  += __shfl_down(dcg,  off, 64);
        idcg += __shfl_down(idcg, off, 64);
    }
    if ((i & 63) == 0) {
        s_dcg[i >> 6]  = dcg;
        s_idcg[i >> 6] = idcg;
    }
    __syncthreads();   // covers s_gain/s_disc writes AND the wave partials

    const float DCG  = s_dcg[0] + s_dcg[1];
    const float IDCG = fmaxf(s_idcg[0] + s_idcg[1], IDCG_FLOOR);
    const float inv_idcg = 1.0f / IDCG;

    // grad_i = sum_j -|dd*dg| * s * sigmoid(-s*(p_i - p_j)) / IDCG
    float acc = 0.0f;
    #pragma unroll 4
    for (int j = 0; j < L; ++j) {
        const float dd = pdisc - s_disc[j];
        const float dg = gain  - s_gain[j];
        const float lam = fabsf(dd * dg);
        const float dl = lb - s_label[j];
        const float s  = (dl > 0.0f) ? 1.0f : ((dl < 0.0f) ? -1.0f : 0.0f);
        const float pd = s * (p - s_pred[j]);
        // sigmoid(-pd) = 1 / (1 + exp(pd))
        const float sg = 1.0f / (1.0f + __expf(pd));
        acc -= lam * s * sg;
    }

    out_grad[base + i] = acc * inv_idcg;
    if (i == 0) out_loss[b] = (IDCG - DCG) * inv_idcg;
}

extern "C" void kernel_launch(void* const* d_in, const int* in_sizes, int n_in,
                              void* d_out, int out_size, void* d_ws, size_t ws_size,
                              hipStream_t stream) {
    const float* logit = (const float*)d_in[0];
    const float* label = (const float*)d_in[1];
    float* out      = (float*)d_out;
    float* out_loss = out;          // first NSESS elements
    float* out_grad = out + NSESS;  // next NSESS*L elements

    lambdarank_ndcg_kernel<<<NSESS, L, 0, stream>>>(logit, label, out_loss, out_grad);
}

// Round 3
// 75.329 us; speedup vs baseline: 1.1695x; 1.1695x over previous
//
#include <hip/hip_runtime.h>
#include <math.h>

#define NSESS 2048
#define L 128
#define IDCG_FLOOR 1e-5f
#define LOG2E 1.44269504088896340736f

// Broadcast lane `j` (uniform) of x to all lanes via v_readlane (SGPR result).
__device__ __forceinline__ float rl_f(float x, int j) {
    return __uint_as_float((unsigned)__builtin_amdgcn_readlane((int)__float_as_uint(x), j));
}
__device__ __forceinline__ unsigned rl_u(unsigned x, int j) {
    return (unsigned)__builtin_amdgcn_readlane((int)x, j);
}
// Single v_exp_f32 (input already scaled by log2e); avoids ocml denorm fixup code.
__device__ __forceinline__ float fast_exp2(float x) {
    float r;
    asm("v_exp_f32 %0, %1" : "=v"(r) : "v"(x));
    return r;
}

__global__ __launch_bounds__(64) void lambdarank_ndcg_kernel(
    const float* __restrict__ logit,
    const float* __restrict__ label,
    float* __restrict__ out_loss,   // [NSESS]
    float* __restrict__ out_grad)   // [NSESS * L]
{
    const int b    = blockIdx.x;
    const int lane = threadIdx.x;        // 0..63
    const int base = b * L;

    // Each lane owns items i0 = lane, i1 = lane + 64.
    const float p0  = logit[base + lane];
    const float p1  = logit[base + 64 + lane];
    const float lb0 = label[base + lane];
    const float lb1 = label[base + 64 + lane];
    const int   il0 = (int)lb0;          // labels are exact ints 0..4
    const int   il1 = (int)lb1;
    const float g0  = (float)(1 << il0); // gain = 2^label, exact
    const float g1  = (float)(1 << il1);

    // ---------- pred ranks: stable descending via 64-bit keys ----------
    // monotone map float -> u32 (ascending), flip for descending, append index
    // for the stable tie-break. rank_i = #{j : K_j < K_i}.
    const unsigned bb0  = __float_as_uint(p0);
    const unsigned bb1  = __float_as_uint(p1);
    const unsigned asc0 = (bb0 & 0x80000000u) ? ~bb0 : (bb0 | 0x80000000u);
    const unsigned asc1 = (bb1 & 0x80000000u) ? ~bb1 : (bb1 | 0x80000000u);
    const unsigned long long K0 =
        (((unsigned long long)(~asc0)) << 7) | (unsigned)lane;
    const unsigned long long K1 =
        (((unsigned long long)(~asc1)) << 7) | (unsigned)(lane + 64);

    int rp0 = 0, rp1 = 0;
    #pragma unroll 8
    for (int j = 0; j < 64; ++j) {
        const unsigned lo = rl_u((unsigned)K0, j);
        const unsigned hi = rl_u((unsigned)(K0 >> 32), j);
        const unsigned long long Kj = (((unsigned long long)hi) << 32) | lo;
        rp0 += (Kj < K0);
        rp1 += (Kj < K1);
    }
    #pragma unroll 8
    for (int j = 0; j < 64; ++j) {
        const unsigned lo = rl_u((unsigned)K1, j);
        const unsigned hi = rl_u((unsigned)(K1 >> 32), j);
        const unsigned long long Kj = (((unsigned long long)hi) << 32) | lo;
        rp0 += (Kj < K0);
        rp1 += (Kj < K1);
    }

    // ---------- label ranks: ballot histogram over the 5 label values ----------
    const unsigned long long lane_lt = (1ull << lane) - 1ull;
    int rl0 = 0, rl1 = 0;
    {
        int sumG = 0; // count of items with label strictly greater than v
        #pragma unroll
        for (int v = 4; v >= 0; --v) {
            const unsigned long long m0 = __ballot(il0 == v);
            const unsigned long long m1 = __ballot(il1 == v);
            if (il0 == v) rl0 = sumG + __popcll(m0 & lane_lt);
            if (il1 == v) rl1 = sumG + __popcll(m0) + __popcll(m1 & lane_lt);
            sumG += __popcll(m0) + __popcll(m1);
        }
    }

    // ---------- discounts ----------
    const float pd0 = __builtin_amdgcn_rcpf(log2f((float)(rp0 + 2)));
    const float pd1 = __builtin_amdgcn_rcpf(log2f((float)(rp1 + 2)));
    const float ld0 = __builtin_amdgcn_rcpf(log2f((float)(rl0 + 2)));
    const float ld1 = __builtin_amdgcn_rcpf(log2f((float)(rl1 + 2)));

    // ---------- DCG / IDCG wave reduction ----------
    float dcg  = g0 * pd0 + g1 * pd1;
    float idcg = g0 * ld0 + g1 * ld1;
    #pragma unroll
    for (int off = 32; off > 0; off >>= 1) {
        dcg  += __shfl_xor(dcg,  off, 64);
        idcg += __shfl_xor(idcg, off, 64);
    }
    const float IDCG     = fmaxf(idcg, IDCG_FLOOR);
    const float inv_idcg = __builtin_amdgcn_rcpf(IDCG);

    // ---------- lambda loop ----------
    // term_ij = |dd*dg| * ([g_i < g_j] - sigmoid(-(p_i - p_j)))
    // (sign factor folded; label-equal pairs vanish because dg = 0)
    const float ps0 = p0 * LOG2E;
    const float ps1 = p1 * LOG2E;
    float acc0 = 0.0f, acc1 = 0.0f;

    #pragma unroll 4
    for (int j = 0; j < 64; ++j) {   // sources: slot-0 items (idx j)
        const float pj = rl_f(ps0, j);
        const float gj = rl_f(g0,  j);
        const float dj = rl_f(pd0, j);
        {
            const float e  = fast_exp2(ps0 - pj);
            const float sg = __builtin_amdgcn_rcpf(1.0f + e);
            const float t  = (pd0 - dj) * (g0 - gj);
            const float nm = ((g0 < gj) ? 1.0f : 0.0f) - sg;
            acc0 += fabsf(t) * nm;
        }
        {
            const float e  = fast_exp2(ps1 - pj);
            const float sg = __builtin_amdgcn_rcpf(1.0f + e);
            const float t  = (pd1 - dj) * (g1 - gj);
            const float nm = ((g1 < gj) ? 1.0f : 0.0f) - sg;
            acc1 += fabsf(t) * nm;
        }
    }
    #pragma unroll 4
    for (int j = 0; j < 64; ++j) {   // sources: slot-1 items (idx 64+j)
        const float pj = rl_f(ps1, j);
        const float gj = rl_f(g1,  j);
        const float dj = rl_f(pd1, j);
        {
            const float e  = fast_exp2(ps0 - pj);
            const float sg = __builtin_amdgcn_rcpf(1.0f + e);
            const float t  = (pd0 - dj) * (g0 - gj);
            const float nm = ((g0 < gj) ? 1.0f : 0.0f) - sg;
            acc0 += fabsf(t) * nm;
        }
        {
            const float e  = fast_exp2(ps1 - pj);
            const float sg = __builtin_amdgcn_rcpf(1.0f + e);
            const float t  = (pd1 - dj) * (g1 - gj);
            const float nm = ((g1 < gj) ? 1.0f : 0.0f) - sg;
            acc1 += fabsf(t) * nm;
        }
    }

    out_grad[base + lane]      = acc0 * inv_idcg;
    out_grad[base + 64 + lane] = acc1 * inv_idcg;
    if (lane == 0) out_loss[b] = (IDCG - dcg) * inv_idcg;
}

extern "C" void kernel_launch(void* const* d_in, const int* in_sizes, int n_in,
                              void* d_out, int out_size, void* d_ws, size_t ws_size,
                              hipStream_t stream) {
    const float* logit = (const float*)d_in[0];
    const float* label = (const float*)d_in[1];
    float* out      = (float*)d_out;
    float* out_loss = out;          // first NSESS elements
    float* out_grad = out + NSESS;  // next NSESS*L elements

    lambdarank_ndcg_kernel<<<NSESS, 64, 0, stream>>>(logit, label, out_loss, out_grad);
}

// Round 9
// 72.509 us; speedup vs baseline: 1.2149x; 1.0389x over previous
//
#include <hip/hip_runtime.h>
#include <math.h>

#define NSESS 2048
#define L 128
#define IDCG_FLOOR 1e-5f
#define LOG2E 1.44269504088896340736f

// Broadcast lane `j` (uniform) of x to all lanes via v_readlane (SGPR result).
__device__ __forceinline__ float rl_f(float x, int j) {
    return __uint_as_float((unsigned)__builtin_amdgcn_readlane((int)__float_as_uint(x), j));
}
__device__ __forceinline__ unsigned rl_u(unsigned x, int j) {
    return (unsigned)__builtin_amdgcn_readlane((int)x, j);
}
// Raw transcendentals (safe here: inputs are normal-range, no denorm fixup needed).
__device__ __forceinline__ float fexp2(float x){ float r; asm("v_exp_f32 %0, %1":"=v"(r):"v"(x)); return r; }
__device__ __forceinline__ float flog2(float x){ float r; asm("v_log_f32 %0, %1":"=v"(r):"v"(x)); return r; }
__device__ __forceinline__ float frcp (float x){ float r; asm("v_rcp_f32 %0, %1":"=v"(r):"v"(x)); return r; }

__global__ __launch_bounds__(64) void lambdarank_ndcg_kernel(
    const float* __restrict__ logit,
    const float* __restrict__ label,
    float* __restrict__ out_loss,   // [NSESS]
    float* __restrict__ out_grad)   // [NSESS * L]
{
    const int b    = blockIdx.x;
    const int lane = threadIdx.x;        // 0..63
    const int base = b * L;

    // Each lane owns items i0 = 2*lane (slot 0), i1 = 2*lane+1 (slot 1)
    // -> float2 vector loads/stores.
    const float2 pv = ((const float2*)(logit + base))[lane];
    const float2 lv = ((const float2*)(label + base))[lane];
    const float p0  = pv.x,  p1  = pv.y;
    const float lb0 = lv.x,  lb1 = lv.y;
    const int   il0 = (int)lb0;          // labels are exact ints 0..4
    const int   il1 = (int)lb1;
    const float g0  = (float)(1 << il0); // gain = 2^label, exact
    const float g1  = (float)(1 << il1);

    // ---------- pred ranks: stable descending via 64-bit keys ----------
    const unsigned bb0  = __float_as_uint(p0);
    const unsigned bb1  = __float_as_uint(p1);
    const unsigned asc0 = (bb0 & 0x80000000u) ? ~bb0 : (bb0 | 0x80000000u);
    const unsigned asc1 = (bb1 & 0x80000000u) ? ~bb1 : (bb1 | 0x80000000u);
    const unsigned long long K0 =
        (((unsigned long long)(~asc0)) << 7) | (unsigned)(2 * lane);
    const unsigned long long K1 =
        (((unsigned long long)(~asc1)) << 7) | (unsigned)(2 * lane + 1);

    int rp0 = 0, rp1 = 0;
    #pragma unroll 8
    for (int j = 0; j < 64; ++j) {
        const unsigned lo = rl_u((unsigned)K0, j);
        const unsigned hi = rl_u((unsigned)(K0 >> 32), j);
        const unsigned long long Kj = (((unsigned long long)hi) << 32) | lo;
        rp0 += (Kj < K0);
        rp1 += (Kj < K1);
    }
    #pragma unroll 8
    for (int j = 0; j < 64; ++j) {
        const unsigned lo = rl_u((unsigned)K1, j);
        const unsigned hi = rl_u((unsigned)(K1 >> 32), j);
        const unsigned long long Kj = (((unsigned long long)hi) << 32) | lo;
        rp0 += (Kj < K0);
        rp1 += (Kj < K1);
    }

    // ---------- label ranks: ballot histogram over the 5 label values ----------
    const unsigned long long lane_lt = (1ull << lane) - 1ull;
    const unsigned long long lane_le = lane_lt | (1ull << lane);
    int rl0 = 0, rl1 = 0;
    {
        int sumG = 0; // count of items with label strictly greater than v
        #pragma unroll
        for (int v = 4; v >= 0; --v) {
            const unsigned long long m0 = __ballot(il0 == v);
            const unsigned long long m1 = __ballot(il1 == v);
            // item i0 = 2*lane: lower-index equals are slot0 lanes<lane, slot1 lanes<lane
            if (il0 == v) rl0 = sumG + __popcll(m0 & lane_lt) + __popcll(m1 & lane_lt);
            // item i1 = 2*lane+1: slot0 lanes<=lane, slot1 lanes<lane
            if (il1 == v) rl1 = sumG + __popcll(m0 & lane_le) + __popcll(m1 & lane_lt);
            sumG += __popcll(m0) + __popcll(m1);
        }
    }

    // ---------- discounts (once per item; inputs exact ints in [2,129]) ----------
    const float pd0 = frcp(flog2((float)(rp0 + 2)));
    const float pd1 = frcp(flog2((float)(rp1 + 2)));
    const float ld0 = frcp(flog2((float)(rl0 + 2)));
    const float ld1 = frcp(flog2((float)(rl1 + 2)));

    // ---------- DCG / IDCG wave reduction ----------
    float dcg  = g0 * pd0 + g1 * pd1;
    float idcg = g0 * ld0 + g1 * ld1;
    #pragma unroll
    for (int off = 32; off > 0; off >>= 1) {
        dcg  += __shfl_xor(dcg,  off, 64);
        idcg += __shfl_xor(idcg, off, 64);
    }
    const float IDCG     = fmaxf(idcg, IDCG_FLOOR);
    const float inv_idcg = frcp(IDCG);

    // ---------- per-item exp precompute: exp(p_i - p_j) = E_i * Einv_j ----------
    const float ps0   = p0 * LOG2E;
    const float ps1   = p1 * LOG2E;
    const float E0    = fexp2(ps0);
    const float E1    = fexp2(ps1);
    const float Einv0 = fexp2(-ps0);
    const float Einv1 = fexp2(-ps1);

    // ---------- lambda loop ----------
    // term_ij = |dd*dg| * ([g_i < g_j] - sigmoid(-(p_i-p_j)))
    // sigmoid(-(p_i-p_j)) = 1 / (1 + E_i * Einv_j)
    float acc0 = 0.0f, acc1 = 0.0f;

    #pragma unroll 8
    for (int j = 0; j < 64; ++j) {   // sources: slot-0 items
        const float EJ = rl_f(Einv0, j);
        const float gj = rl_f(g0,   j);
        const float dj = rl_f(pd0,  j);
        const float sg0 = frcp(1.0f + E0 * EJ);
        const float sg1 = frcp(1.0f + E1 * EJ);
        const float t0  = (pd0 - dj) * (g0 - gj);
        const float t1  = (pd1 - dj) * (g1 - gj);
        const float nm0 = ((g0 < gj) ? 1.0f : 0.0f) - sg0;
        const float nm1 = ((g1 < gj) ? 1.0f : 0.0f) - sg1;
        acc0 = fmaf(fabsf(t0), nm0, acc0);
        acc1 = fmaf(fabsf(t1), nm1, acc1);
    }
    #pragma unroll 8
    for (int j = 0; j < 64; ++j) {   // sources: slot-1 items
        const float EJ = rl_f(Einv1, j);
        const float gj = rl_f(g1,   j);
        const float dj = rl_f(pd1,  j);
        const float sg0 = frcp(1.0f + E0 * EJ);
        const float sg1 = frcp(1.0f + E1 * EJ);
        const float t0  = (pd0 - dj) * (g0 - gj);
        const float t1  = (pd1 - dj) * (g1 - gj);
        const float nm0 = ((g0 < gj) ? 1.0f : 0.0f) - sg0;
        const float nm1 = ((g1 < gj) ? 1.0f : 0.0f) - sg1;
        acc0 = fmaf(fabsf(t0), nm0, acc0);
        acc1 = fmaf(fabsf(t1), nm1, acc1);
    }

    ((float2*)(out_grad + base))[lane] = make_float2(acc0 * inv_idcg, acc1 * inv_idcg);
    if (lane == 0) out_loss[b] = (IDCG - dcg) * inv_idcg;
}

extern "C" void kernel_launch(void* const* d_in, const int* in_sizes, int n_in,
                              void* d_out, int out_size, void* d_ws, size_t ws_size,
                              hipStream_t stream) {
    const float* logit = (const float*)d_in[0];
    const float* label = (const float*)d_in[1];
    float* out      = (float*)d_out;
    float* out_loss = out;          // first NSESS elements
    float* out_grad = out + NSESS;  // next NSESS*L elements

    lambdarank_ndcg_kernel<<<NSESS, 64, 0, stream>>>(logit, label, out_loss, out_grad);
}

// Round 10
// 71.388 us; speedup vs baseline: 1.2340x; 1.0157x over previous
//
#include <hip/hip_runtime.h>
#include <math.h>

#define NSESS 2048
#define L 128
#define IDCG_FLOOR 1e-5f
#define LOG2E 1.44269504088896340736f

typedef float f32x2 __attribute__((ext_vector_type(2)));

// Broadcast lane `j` (uniform) of x to all lanes via v_readlane (SGPR result).
__device__ __forceinline__ float rl_f(float x, int j) {
    return __uint_as_float((unsigned)__builtin_amdgcn_readlane((int)__float_as_uint(x), j));
}
__device__ __forceinline__ unsigned rl_u(unsigned x, int j) {
    return (unsigned)__builtin_amdgcn_readlane((int)x, j);
}
// Raw transcendentals (safe here: inputs are normal-range, no denorm fixup needed).
__device__ __forceinline__ float fexp2(float x){ float r; asm("v_exp_f32 %0, %1":"=v"(r):"v"(x)); return r; }
__device__ __forceinline__ float flog2(float x){ float r; asm("v_log_f32 %0, %1":"=v"(r):"v"(x)); return r; }
__device__ __forceinline__ float frcp (float x){ float r; asm("v_rcp_f32 %0, %1":"=v"(r):"v"(x)); return r; }

__global__ __launch_bounds__(64) void lambdarank_ndcg_kernel(
    const float* __restrict__ logit,
    const float* __restrict__ label,
    float* __restrict__ out_loss,   // [NSESS]
    float* __restrict__ out_grad)   // [NSESS * L]
{
    const int b    = blockIdx.x;
    const int lane = threadIdx.x;        // 0..63
    const int base = b * L;

    // Each lane owns items i0 = 2*lane (slot 0), i1 = 2*lane+1 (slot 1)
    // -> float2 vector loads/stores.
    const float2 pv = ((const float2*)(logit + base))[lane];
    const float2 lv = ((const float2*)(label + base))[lane];
    const float p0  = pv.x,  p1  = pv.y;
    const float lb0 = lv.x,  lb1 = lv.y;
    const int   il0 = (int)lb0;          // labels are exact ints 0..4
    const int   il1 = (int)lb1;
    const float g0  = (float)(1 << il0); // gain = 2^label, exact
    const float g1  = (float)(1 << il1);

    // ---------- pred ranks: stable descending via 64-bit keys ----------
    const unsigned bb0  = __float_as_uint(p0);
    const unsigned bb1  = __float_as_uint(p1);
    const unsigned asc0 = (bb0 & 0x80000000u) ? ~bb0 : (bb0 | 0x80000000u);
    const unsigned asc1 = (bb1 & 0x80000000u) ? ~bb1 : (bb1 | 0x80000000u);
    const unsigned long long K0 =
        (((unsigned long long)(~asc0)) << 7) | (unsigned)(2 * lane);
    const unsigned long long K1 =
        (((unsigned long long)(~asc1)) << 7) | (unsigned)(2 * lane + 1);

    int rp0 = 0, rp1 = 0;
    #pragma unroll 8
    for (int j = 0; j < 64; ++j) {
        const unsigned lo = rl_u((unsigned)K0, j);
        const unsigned hi = rl_u((unsigned)(K0 >> 32), j);
        const unsigned long long Kj = (((unsigned long long)hi) << 32) | lo;
        rp0 += (Kj < K0);
        rp1 += (Kj < K1);
    }
    #pragma unroll 8
    for (int j = 0; j < 64; ++j) {
        const unsigned lo = rl_u((unsigned)K1, j);
        const unsigned hi = rl_u((unsigned)(K1 >> 32), j);
        const unsigned long long Kj = (((unsigned long long)hi) << 32) | lo;
        rp0 += (Kj < K0);
        rp1 += (Kj < K1);
    }

    // ---------- label ranks: ballot histogram over the 5 label values ----------
    const unsigned long long lane_lt = (1ull << lane) - 1ull;
    const unsigned long long lane_le = lane_lt | (1ull << lane);
    int rl0 = 0, rl1 = 0;
    {
        int sumG = 0; // count of items with label strictly greater than v
        #pragma unroll
        for (int v = 4; v >= 0; --v) {
            const unsigned long long m0 = __ballot(il0 == v);
            const unsigned long long m1 = __ballot(il1 == v);
            // item i0 = 2*lane: lower-index equals are slot0 lanes<lane, slot1 lanes<lane
            if (il0 == v) rl0 = sumG + __popcll(m0 & lane_lt) + __popcll(m1 & lane_lt);
            // item i1 = 2*lane+1: slot0 lanes<=lane, slot1 lanes<lane
            if (il1 == v) rl1 = sumG + __popcll(m0 & lane_le) + __popcll(m1 & lane_lt);
            sumG += __popcll(m0) + __popcll(m1);
        }
    }

    // ---------- discounts (once per item; inputs exact ints in [2,129]) ----------
    const float pd0 = frcp(flog2((float)(rp0 + 2)));
    const float pd1 = frcp(flog2((float)(rp1 + 2)));
    const float ld0 = frcp(flog2((float)(rl0 + 2)));
    const float ld1 = frcp(flog2((float)(rl1 + 2)));

    // ---------- DCG / IDCG wave reduction ----------
    float dcg  = g0 * pd0 + g1 * pd1;
    float idcg = g0 * ld0 + g1 * ld1;
    #pragma unroll
    for (int off = 32; off > 0; off >>= 1) {
        dcg  += __shfl_xor(dcg,  off, 64);
        idcg += __shfl_xor(idcg, off, 64);
    }
    const float IDCG     = fmaxf(idcg, IDCG_FLOOR);
    const float inv_idcg = frcp(IDCG);

    // ---------- per-item exp precompute: exp(p_i - p_j) = E_i * Einv_j ----------
    const float ps0   = p0 * LOG2E;
    const float ps1   = p1 * LOG2E;
    const float E0    = fexp2(ps0);
    const float E1    = fexp2(ps1);
    const float Einv0 = fexp2(-ps0);
    const float Einv1 = fexp2(-ps1);

    // ---------- lambda loop (packed 2-wide: slot0/slot1 in one f32x2 chain) ----
    // term_ij = |dd| * ( max(gj-g, 0) - |gj-g| * sg ),  sg = 1/(1 + E_i*Einv_j)
    // (exact fold of |dd*dg|*([g<gj]-sg):  |dg|*[g<gj] == (gj-g)+ )
    const f32x2 E01  = {E0, E1};
    const f32x2 g01  = {g0, g1};
    const f32x2 pd01 = {pd0, pd1};
    f32x2 acc = {0.0f, 0.0f};

    #pragma unroll 8
    for (int j = 0; j < 64; ++j) {   // sources: slot-0 items
        const float EJ = rl_f(Einv0, j);
        const float gj = rl_f(g0,   j);
        const float dj = rl_f(pd0,  j);
        const f32x2 t  = E01 * EJ + 1.0f;            // pk_fma
        const f32x2 sg = {frcp(t.x), frcp(t.y)};
        const f32x2 u  = gj - g01;                    // pk_sub (splat)
        const f32x2 A  = __builtin_elementwise_max(u, (f32x2)(0.0f));
        const f32x2 au = __builtin_elementwise_max(u, -u);   // |u| in pk domain
        const f32x2 dd = pd01 - dj;
        const f32x2 ad = __builtin_elementwise_max(dd, -dd); // |dd|
        acc += ad * (A - au * sg);                    // pk_mul/pk_fma chain
    }
    #pragma unroll 8
    for (int j = 0; j < 64; ++j) {   // sources: slot-1 items
        const float EJ = rl_f(Einv1, j);
        const float gj = rl_f(g1,   j);
        const float dj = rl_f(pd1,  j);
        const f32x2 t  = E01 * EJ + 1.0f;
        const f32x2 sg = {frcp(t.x), frcp(t.y)};
        const f32x2 u  = gj - g01;
        const f32x2 A  = __builtin_elementwise_max(u, (f32x2)(0.0f));
        const f32x2 au = __builtin_elementwise_max(u, -u);
        const f32x2 dd = pd01 - dj;
        const f32x2 ad = __builtin_elementwise_max(dd, -dd);
        acc += ad * (A - au * sg);
    }

    const f32x2 r = acc * inv_idcg;
    ((f32x2*)(out_grad + base))[lane] = r;
    if (lane == 0) out_loss[b] = (IDCG - dcg) * inv_idcg;
}

extern "C" void kernel_launch(void* const* d_in, const int* in_sizes, int n_in,
                              void* d_out, int out_size, void* d_ws, size_t ws_size,
                              hipStream_t stream) {
    const float* logit = (const float*)d_in[0];
    const float* label = (const float*)d_in[1];
    float* out      = (float*)d_out;
    float* out_loss = out;          // first NSESS elements
    float* out_grad = out + NSESS;  // next NSESS*L elements

    lambdarank_ndcg_kernel<<<NSESS, 64, 0, stream>>>(logit, label, out_loss, out_grad);
}